// Round 3
// baseline (267.150 us; speedup 1.0000x reference)
//
#include <hip/hip_runtime.h>
#include <math.h>
#include <stdint.h>

#define B_ 4
#define L_ 1024
#define DM 512
#define NHA 32
#define HD 16
#define DI 1024
#define DSTATE 64
#define HDIM_ 64
#define NHM 16
#define DCONV 4
#define CONVCH 1152
#define DINPROJ 2192
#define NTOK (B_*L_)
#define QC 64
#define NC (L_/QC)
#define QKVS 5920            // mega zxbcdt row stride: 1536 + 2192 + 2192

typedef __bf16 bf16x8 __attribute__((ext_vector_type(8)));
typedef float f32x4 __attribute__((ext_vector_type(4)));
typedef unsigned short ushort8 __attribute__((ext_vector_type(8)));
typedef unsigned short ushort4v __attribute__((ext_vector_type(4)));
typedef __fp16 fp16x2 __attribute__((ext_vector_type(2)));
typedef _Float16 f16x4 __attribute__((ext_vector_type(4)));
typedef _Float16 f16x8 __attribute__((ext_vector_type(8)));

__device__ __forceinline__ float siluf(float x) {
    return x / (1.0f + __expf(-x));
}

__device__ __forceinline__ unsigned short f2bf(float f) {
    unsigned u = __float_as_uint(f);
    unsigned r = (u + 0x7FFFu + ((u >> 16) & 1u)) >> 16;
    return (unsigned short)r;
}

__device__ __forceinline__ float bf2f(unsigned short u) {
    return __uint_as_float((unsigned)u << 16);
}

__device__ __forceinline__ void cvt8(const float* src, unsigned short* dst) {
    float4 a = ((const float4*)src)[0];
    float4 b = ((const float4*)src)[1];
    ushort8 o;
    o[0] = f2bf(a.x); o[1] = f2bf(a.y); o[2] = f2bf(a.z); o[3] = f2bf(a.w);
    o[4] = f2bf(b.x); o[5] = f2bf(b.y); o[6] = f2bf(b.z); o[7] = f2bf(b.w);
    *(ushort8*)dst = o;
}

// async global->LDS 16B
__device__ __forceinline__ void gload16(const void* g, void* l) {
    auto gp = reinterpret_cast<const __attribute__((address_space(1))) unsigned int*>(
        reinterpret_cast<uintptr_t>(g));
    auto lp = reinterpret_cast<__attribute__((address_space(3))) unsigned int*>(
        reinterpret_cast<uintptr_t>(l));
    __builtin_amdgcn_global_load_lds(gp, lp, 16, 0, 0);
}

// LDS chunk swizzle: slot = chunk ^ sw(row). Old (row&3) left rows {0,4,8,12}
// on the same 4 banks (4-way conflict, 3.1M counter hits); (row^(row>>2))&3
// makes same-parity rows hit distinct slots -> 2-way aliasing (free, m136).
__device__ __forceinline__ int swz3(int row) {
    return (row ^ (row >> 2)) & 3;
}

// ---- fused f32->bf16: h + qkv_w + attn_out_w + inproj_fwd + inproj_bwd ----
#define S0 262144
#define S1 (S0 + 98304)
#define S2 (S1 + 32768)
#define S3 (S2 + 140288)
#define S4 (S3 + 140288)
__global__ void cvt_all_kernel(const float* __restrict__ h, unsigned short* __restrict__ hB,
                               const float* __restrict__ w1, unsigned short* __restrict__ d1,
                               const float* __restrict__ w2, unsigned short* __restrict__ d2,
                               const float* __restrict__ w3, unsigned short* __restrict__ d3,
                               const float* __restrict__ w4, unsigned short* __restrict__ d4) {
    int i = blockIdx.x * blockDim.x + threadIdx.x;
    const float* src; unsigned short* dst; int off;
    if (i < S0)      { src = h;  dst = hB; off = i; }
    else if (i < S1) { src = w1; dst = d1; off = i - S0; }
    else if (i < S2) { src = w2; dst = d2; off = i - S1; }
    else if (i < S3) { src = w3; dst = d3; off = i - S2; }
    else             { src = w4; dst = d4; off = i - S3; }
    cvt8(src + (size_t)off * 8, dst + (size_t)off * 8);
}

// ---- outproj concat cvt: fwd+bwd into [512][2048] bf16, one launch ----
__global__ void cvt_outproj_kernel(const float* __restrict__ fw, const float* __restrict__ bw,
                                   unsigned short* __restrict__ dst) {
    int i = blockIdx.x * blockDim.x + threadIdx.x;
    const int n8 = DM * DI / 8;
    int half = i >= n8;
    int off = half ? i - n8 : i;
    const float* src = half ? bw : fw;
    int e = off * 8;
    int r = e / DI, c = e % DI;
    cvt8(src + e, dst + (size_t)r * 2048 + half * 1024 + c);
}

// ---------- Staged MFMA GEMM: C[M,N] = Ab[M,K] @ Wb[N,K]^T (+bias cols<biasN)
// launch_bounds(256,4): cap unified VGPR+AGPR at 128 -> 4 blocks/CU resident
// (was 132 regs -> 2 blocks/CU, the latency-bound occupancy ceiling).
// SPLITK: grid.z = 2 halves of K, each writes its own f32 C buffer
// (summed downstream) -> doubles resident blocks for skinny-N deep-K GEMMs.
template <int BN, bool OBF16, bool SWZ, bool SPLITK>
__global__ __launch_bounds__(256, 4) void gemm_mfma_staged(
        const unsigned short* __restrict__ Ab, const unsigned short* __restrict__ Wb,
        const float* __restrict__ bias, int biasN, void* __restrict__ Cout,
        int M, int N, int K) {
    constexpr int BM = 128, BK = 32;
    constexpr int NF = BN / 32;
    constexpr int BLOADS = BN / 64;
    __shared__ unsigned short As[2][BM * BK];
    __shared__ unsigned short Bs[2][BN * BK];

    const int tid = threadIdx.x;
    const int wave = tid >> 6, lane = tid & 63;
    const int l15 = lane & 15, g = lane >> 4;
    const int wm = wave >> 1, wn = wave & 1;
    int m0, n0;
    if constexpr (SWZ) {
        int d = blockIdx.x;
        int xcd = d & 7, jj = d >> 3;
        n0 = (xcd * 6 + jj % 6) * BN;
        m0 = (jj / 6) * BM;
    } else {
        m0 = blockIdx.y * BM;
        n0 = blockIdx.x * BN;
    }

    f32x4 acc[4][NF];
    #pragma unroll
    for (int mi = 0; mi < 4; ++mi)
        #pragma unroll
        for (int nj = 0; nj < NF; ++nj) acc[mi][nj] = (f32x4){0.f, 0.f, 0.f, 0.f};

    auto stage = [&](int bufi, int k0) {
        #pragma unroll
        for (int i = 0; i < 2; ++i) {
            int c = (wave * 2 + i) * 64 + lane;
            int row = c >> 2;
            int kc = ((c & 3) ^ swz3(row)) * 8;      // pre-swizzled source
            gload16(Ab + (size_t)(m0 + row) * K + k0 + kc,
                    &As[bufi][(wave * 2 + i) * 64 * 8]);
        }
        #pragma unroll
        for (int i = 0; i < BLOADS; ++i) {
            int c = (wave * BLOADS + i) * 64 + lane;
            int row = c >> 2;
            int kc = ((c & 3) ^ swz3(row)) * 8;
            int rn = n0 + row; if (rn >= N) rn = N - 1;
            gload16(Wb + (size_t)rn * K + k0 + kc,
                    &Bs[bufi][(wave * BLOADS + i) * 64 * 8]);
        }
    };

    const int kBeg = SPLITK ? blockIdx.z * (K >> 1) : 0;
    const int kLen = SPLITK ? (K >> 1) : K;

    int cur = 0;
    stage(0, kBeg);
    __syncthreads();
    for (int kk = 0; kk < kLen; kk += BK) {
        if (kk + BK < kLen) stage(cur ^ 1, kBeg + kk + BK);
        const unsigned short* Ac = As[cur];
        const unsigned short* Bc = Bs[cur];
        bf16x8 af[4];
        #pragma unroll
        for (int mi = 0; mi < 4; ++mi) {
            int ar = wm * 64 + mi * 16 + l15;
            af[mi] = *(const bf16x8*)(Ac + ar * BK + ((g ^ swz3(ar)) * 8));
        }
        bf16x8 bfr[NF];
        #pragma unroll
        for (int nj = 0; nj < NF; ++nj) {
            int br = wn * (BN / 2) + nj * 16 + l15;
            bfr[nj] = *(const bf16x8*)(Bc + br * BK + ((g ^ swz3(br)) * 8));
        }
        #pragma unroll
        for (int mi = 0; mi < 4; ++mi)
            #pragma unroll
            for (int nj = 0; nj < NF; ++nj)
                acc[mi][nj] = __builtin_amdgcn_mfma_f32_16x16x32_bf16(af[mi], bfr[nj], acc[mi][nj], 0, 0, 0);
        __syncthreads();
        cur ^= 1;
    }

    float* CoutF = (float*)Cout;
    if constexpr (SPLITK) CoutF += (size_t)blockIdx.z * M * N;

    #pragma unroll
    for (int mi = 0; mi < 4; ++mi) {
        int rbase = m0 + wm * 64 + mi * 16 + g * 4;
        #pragma unroll
        for (int nj = 0; nj < NF; ++nj) {
            int col = n0 + wn * (BN / 2) + nj * 16 + l15;
            if (col < N) {
                float bv = (bias && col < biasN && (!SPLITK || blockIdx.z == 0)) ? bias[col] : 0.f;
                #pragma unroll
                for (int r = 0; r < 4; ++r) {
                    float v = acc[mi][nj][r] + bv;
                    if constexpr (OBF16)
                        ((unsigned short*)Cout)[(size_t)(rbase + r) * N + col] = f2bf(v);
                    else
                        CoutF[(size_t)(rbase + r) * N + col] = v;
                }
            }
        }
    }
}

// ---------------- MFMA Attention (flash, d=16, fp16 mfma) ----------------
#define KP 24
#define VP 132
__global__ __launch_bounds__(256) void attn_mfma_kernel(const unsigned short* __restrict__ qkv,
                                                        unsigned short* __restrict__ ob) {
    const int n = blockIdx.x;
    const int xcd = n & 7;
    const int j = n >> 3;
    const int bh = ((j >> 4) << 3) + xcd;
    const int qt = j & 15;
    const int h = bh & 31;
    const int b = bh >> 5;
    const int tid = threadIdx.x;
    const int wave = tid >> 6, lane = tid & 63;
    const int l15 = lane & 15, g = lane >> 4;

    __shared__ _Float16 Ksm[128 * KP];
    __shared__ _Float16 VsmT[16 * VP];

    const unsigned short* base = qkv + (size_t)b * L_ * QKVS;
    const int qrow = qt * 64 + wave * 16 + l15;

    f16x4 qf;
    {
        ushort4v qv = *(const ushort4v*)(base + (size_t)qrow * QKVS + h * 16 + g * 4);
        fp16x2 qa = __builtin_amdgcn_cvt_pkrtz(bf2f(qv[0]) * 0.25f, bf2f(qv[1]) * 0.25f);
        fp16x2 qb = __builtin_amdgcn_cvt_pkrtz(bf2f(qv[2]) * 0.25f, bf2f(qv[3]) * 0.25f);
        qf[0] = (_Float16)qa[0]; qf[1] = (_Float16)qa[1];
        qf[2] = (_Float16)qb[0]; qf[3] = (_Float16)qb[1];
    }
    f32x4 yacc = (f32x4){0.f, 0.f, 0.f, 0.f};
    float s = 0.f;

    const int sk = tid >> 1;
    const int sd = (tid & 1) * 8;

    for (int c0 = 0; c0 < L_; c0 += 128) {
        {
            ushort8 ka = *(const ushort8*)(base + (size_t)(c0 + sk) * QKVS + 512 + h * 16 + sd);
            fp16x2 k0 = __builtin_amdgcn_cvt_pkrtz(bf2f(ka[0]), bf2f(ka[1]));
            fp16x2 k1 = __builtin_amdgcn_cvt_pkrtz(bf2f(ka[2]), bf2f(ka[3]));
            fp16x2 k2 = __builtin_amdgcn_cvt_pkrtz(bf2f(ka[4]), bf2f(ka[5]));
            fp16x2 k3 = __builtin_amdgcn_cvt_pkrtz(bf2f(ka[6]), bf2f(ka[7]));
            f16x8 kv;
            kv[0] = (_Float16)k0[0]; kv[1] = (_Float16)k0[1];
            kv[2] = (_Float16)k1[0]; kv[3] = (_Float16)k1[1];
            kv[4] = (_Float16)k2[0]; kv[5] = (_Float16)k2[1];
            kv[6] = (_Float16)k3[0]; kv[7] = (_Float16)k3[1];
            *(f16x8*)(&Ksm[sk * KP + sd]) = kv;
            ushort8 va = *(const ushort8*)(base + (size_t)(c0 + sk) * QKVS + 1024 + h * 16 + sd);
            #pragma unroll
            for (int jj = 0; jj < 8; ++jj)
                VsmT[(sd + jj) * VP + sk] = (_Float16)bf2f(va[jj]);
        }
        __syncthreads();
        #pragma unroll
        for (int half = 0; half < 2; ++half) {
            f32x4 st[4];
            #pragma unroll
            for (int ks = 0; ks < 4; ++ks) {
                f16x4 kf = *(const f16x4*)(&Ksm[((half * 4 + ks) * 16 + l15) * KP + g * 4]);
                st[ks] = __builtin_amdgcn_mfma_f32_16x16x16f16(kf, qf, (f32x4){0.f,0.f,0.f,0.f}, 0, 0, 0);
            }
            float p[16];
            float cs = 0.f;
            #pragma unroll
            for (int ks = 0; ks < 4; ++ks) {
                #pragma unroll
                for (int r = 0; r < 4; ++r) {
                    p[ks * 4 + r] = __expf(st[ks][r]);
                    cs += p[ks * 4 + r];
                }
            }
            cs += __shfl_xor(cs, 16);
            cs += __shfl_xor(cs, 32);
            s += cs;
            #pragma unroll
            for (int ks = 0; ks < 4; ++ks) {
                fp16x2 plo = __builtin_amdgcn_cvt_pkrtz(p[ks*4+0], p[ks*4+1]);
                fp16x2 phi = __builtin_amdgcn_cvt_pkrtz(p[ks*4+2], p[ks*4+3]);
                f16x4 pf;
                pf[0] = (_Float16)plo[0]; pf[1] = (_Float16)plo[1];
                pf[2] = (_Float16)phi[0]; pf[3] = (_Float16)phi[1];
                f16x4 vf = *(const f16x4*)(&VsmT[l15 * VP + (half * 4 + ks) * 16 + g * 4]);
                yacc = __builtin_amdgcn_mfma_f32_16x16x16f16(vf, pf, yacc, 0, 0, 0);
            }
        }
        __syncthreads();
    }
    float inv = 1.f / s;
    ushort4v o;
    o[0] = f2bf(yacc[0] * inv);
    o[1] = f2bf(yacc[1] * inv);
    o[2] = f2bf(yacc[2] * inv);
    o[3] = f2bf(yacc[3] * inv);
    *(ushort4v*)(ob + (size_t)(b * L_ + qrow) * 512 + h * 16 + g * 4) = o;
}

// -- Causal depthwise conv (+bias+silu), bf16 in/out, both dirs (grid.y) -----
// 4 consecutive l per thread: 7-row window reused across 4 outputs
// (1.75 strided megaA loads per output instead of 4).
__global__ void conv_silu_kernel(const unsigned short* __restrict__ megaA,
                                 const float* __restrict__ cw0, const float* __restrict__ cb0,
                                 const float* __restrict__ cw1, const float* __restrict__ cb1,
                                 unsigned short* __restrict__ out) {
    const int rev = blockIdx.y;
    const float* conv_w = rev ? cw1 : cw0;
    const float* conv_b = rev ? cb1 : cb0;
    const int NC4 = CONVCH / 4;                        // 288
    int idx = blockIdx.x * blockDim.x + threadIdx.x;
    if (idx >= (NTOK / 4) * NC4) return;
    int c4 = (idx % NC4) * 4;
    int lt = idx / NC4;                                // 0..NTOK/4-1
    int l0 = (lt & (L_ / 4 - 1)) * 4;
    int b = lt / (L_ / 4);
    const unsigned short* src = megaA + (size_t)b * L_ * QKVS + 1536 + rev * DINPROJ + 1024 + c4;

    const int wsrow = rev ? l0 : l0 - 3;               // window rows wsrow..wsrow+6
    ushort4v x[7];
    #pragma unroll
    for (int i = 0; i < 7; ++i) {
        int rr = wsrow + i;
        if (rr >= 0 && rr < L_) {
            x[i] = *(const ushort4v*)(src + (size_t)rr * QKVS);
        } else {
            x[i][0] = 0; x[i][1] = 0; x[i][2] = 0; x[i][3] = 0;
        }
    }

    float4 w0 = *(const float4*)(conv_w + (c4 + 0) * 4);
    float4 w1 = *(const float4*)(conv_w + (c4 + 1) * 4);
    float4 w2 = *(const float4*)(conv_w + (c4 + 2) * 4);
    float4 w3 = *(const float4*)(conv_w + (c4 + 3) * 4);
    float4 bias = *(const float4*)(conv_b + c4);
    const float wt[4][4] = {{w0.x, w0.y, w0.z, w0.w}, {w1.x, w1.y, w1.z, w1.w},
                            {w2.x, w2.y, w2.z, w2.w}, {w3.x, w3.y, w3.z, w3.w}};

    unsigned short* ob = out + (size_t)rev * NTOK * CONVCH + (size_t)(b * L_ + l0) * CONVCH + c4;
    #pragma unroll
    for (int jj = 0; jj < 4; ++jj) {
        float4 acc = bias;
        #pragma unroll
        for (int j = 0; j < 4; ++j) {
            int wi = rev ? (jj + 3 - j) : (jj + j);
            acc.x = fmaf(wt[0][j], bf2f(x[wi][0]), acc.x);
            acc.y = fmaf(wt[1][j], bf2f(x[wi][1]), acc.y);
            acc.z = fmaf(wt[2][j], bf2f(x[wi][2]), acc.z);
            acc.w = fmaf(wt[3][j], bf2f(x[wi][3]), acc.w);
        }
        ushort4v o;
        o[0] = f2bf(siluf(acc.x)); o[1] = f2bf(siluf(acc.y));
        o[2] = f2bf(siluf(acc.z)); o[3] = f2bf(siluf(acc.w));
        *(ushort4v*)(ob + (size_t)jj * CONVCH) = o;
    }
}

// ------------- exact fp32 dt, BOTH directions per block (h read once) -------
__global__ void dt_exact_kernel(const float* __restrict__ h,
                                const float* __restrict__ wdt0, const float* __restrict__ bias0,
                                const float* __restrict__ wdt1, const float* __restrict__ bias1,
                                float* __restrict__ dt) {
    const int row = blockIdx.x;
    const int tid = threadIdx.x;
    const int g = tid >> 4, j = tid & 15;
    const float* hr = h + (size_t)row * DM;
    const float* wr0 = wdt0 + (size_t)g * DM;
    const float* wr1 = wdt1 + (size_t)g * DM;
    float s0 = 0.f, s1 = 0.f;
    #pragma unroll 8
    for (int t = 0; t < 32; ++t) {
        int k = j + t * 16;
        float hv = hr[k];
        s0 = fmaf(hv, wr0[k], s0);
        s1 = fmaf(hv, wr1[k], s1);
    }
    s0 += __shfl_xor(s0, 1); s0 += __shfl_xor(s0, 2);
    s0 += __shfl_xor(s0, 4); s0 += __shfl_xor(s0, 8);
    s1 += __shfl_xor(s1, 1); s1 += __shfl_xor(s1, 2);
    s1 += __shfl_xor(s1, 4); s1 += __shfl_xor(s1, 8);
    if (j == 0) {
        float v0 = s0 + bias0[g];
        float v1 = s1 + bias1[g];
        dt[(size_t)row * NHM + g] = (v0 > 20.f) ? v0 : log1pf(__expf(v0));
        dt[(size_t)NTOK * NHM + (size_t)row * NHM + g] = (v1 > 20.f) ? v1 : log1pf(__expf(v1));
    }
}

// ======= Chunked SSD — MFMA, bf16 xbc & y, both dirs (grid.y = dir) =======
__global__ __launch_bounds__(256) void ssd_chunk_kernel(
        const unsigned short* __restrict__ xbcAll, const float* __restrict__ dtAll,
        const float* __restrict__ Al0, const float* __restrict__ Dp0,
        const float* __restrict__ Al1, const float* __restrict__ Dp1,
        unsigned short* __restrict__ y16, float* __restrict__ Sb0, float* __restrict__ Sb1,
        float* __restrict__ Edec) {
    const int dir = blockIdx.y;
    const int rev = dir;
    const unsigned short* xbc = xbcAll + (size_t)dir * NTOK * CONVCH;
    const float* dtb = dtAll + (size_t)dir * NTOK * NHM;
    float* Sbuf = dir ? Sb1 : Sb0;
    unsigned short* y = y16 + (size_t)dir * NTOK * DI;

    const int bid = blockIdx.x;
    const int q = bid & (NC - 1);
    const int bh = bid / NC;
    const int b = bh >> 4, h = bh & 15;
    const int tid = threadIdx.x;
    const int wave = tid >> 6, lane = tid & 63;
    const int l15 = lane & 15, l4 = lane >> 4;

    __shared__ unsigned short Bn[64 * 72];
    __shared__ unsigned short Cn[64 * 72];
    __shared__ unsigned short Btw[64 * 72];
    __shared__ unsigned short Gt[64 * 72];
    __shared__ unsigned short xT[64 * 72];
    __shared__ float sdt[QC], sc[QC], wsv[QC];

    const float A = -__expf((dir ? Al1 : Al0)[h]);
    const float Dh = (dir ? Dp1 : Dp0)[h];
    const int r = tid >> 2, qq = tid & 3;

    #pragma unroll
    for (int j = 0; j < 4; ++j) {
        int qd = qq + j * 4;
        int t = q * QC + r;
        int l = rev ? (L_ - 1 - t) : t;
        const unsigned short* rowp = xbc + (size_t)(b * L_ + l) * CONVCH;
        *(ushort4v*)&Bn[r * 72 + qd * 4] = *(const ushort4v*)(rowp + 1024 + qd * 4);
        *(ushort4v*)&Cn[r * 72 + qd * 4] = *(const ushort4v*)(rowp + 1088 + qd * 4);
    }
    if (tid < QC) {
        int t = q * QC + tid;
        int l = rev ? (L_ - 1 - t) : t;
        sdt[tid] = dtb[(size_t)(b * L_ + l) * NHM + h];
    }
    __syncthreads();
    if (tid == 0) {
        float run = 0.f;
        for (int i = 0; i < QC; ++i) { run += A * sdt[i]; sc[i] = run; }
    }
    __syncthreads();
    if (tid < QC) wsv[tid] = sdt[tid] * __expf(sc[QC - 1] - sc[tid]);
    if (tid == 0) Edec[dir * 1024 + bid] = __expf(sc[QC - 1]);
    __syncthreads();

    {
        int n = tid >> 2, s0 = (tid & 3) * 16;
        ushort8 o0, o1;
        #pragma unroll
        for (int k = 0; k < 8; ++k) {
            o0[k] = f2bf(bf2f(Bn[(s0 + k) * 72 + n]) * wsv[s0 + k]);
            o1[k] = f2bf(bf2f(Bn[(s0 + 8 + k) * 72 + n]) * wsv[s0 + 8 + k]);
        }
        *(ushort8*)&Btw[n * 72 + s0] = o0;
        *(ushort8*)&Btw[n * 72 + s0 + 8] = o1;
    }
    #pragma unroll
    for (int j = 0; j < 4; ++j) {
        int qd = qq + j * 4;
        int t = q * QC + r;
        int l = rev ? (L_ - 1 - t) : t;
        const unsigned short* rowp = xbc + (size_t)(b * L_ + l) * CONVCH + h * 64;
        ushort4v xv = *(const ushort4v*)(rowp + qd * 4);
        xT[(qd * 4 + 0) * 72 + r] = xv[0];
        xT[(qd * 4 + 1) * 72 + r] = xv[1];
        xT[(qd * 4 + 2) * 72 + r] = xv[2];
        xT[(qd * 4 + 3) * 72 + r] = xv[3];
    }
    __syncthreads();

    f32x4 accG[4];
    #pragma unroll
    for (int j = 0; j < 4; ++j) accG[j] = (f32x4){0.f, 0.f, 0.f, 0.f};
    #pragma unroll
    for (int k0 = 0; k0 < 64; k0 += 32) {
        bf16x8 af = *(const bf16x8*)&Bn[(wave * 16 + l15) * 72 + l4 * 8 + k0];
        #pragma unroll
        for (int j = 0; j < 4; ++j) {
            bf16x8 bfj = *(const bf16x8*)&Cn[(j * 16 + l15) * 72 + l4 * 8 + k0];
            accG[j] = __builtin_amdgcn_mfma_f32_16x16x32_bf16(af, bfj, accG[j], 0, 0, 0);
        }
    }
    #pragma unroll
    for (int j = 0; j < 4; ++j) {
        #pragma unroll
        for (int rr = 0; rr < 4; ++rr) {
            int s = wave * 16 + l4 * 4 + rr;
            int i = j * 16 + l15;
            float g = (s <= i) ? accG[j][rr] * sdt[s] * __expf(sc[i] - sc[s]) : 0.f;
            Gt[i * 72 + s] = f2bf(g);
        }
    }
    __syncthreads();

    {
        f32x4 accY[4];
        #pragma unroll
        for (int j = 0; j < 4; ++j) accY[j] = (f32x4){0.f, 0.f, 0.f, 0.f};
        #pragma unroll
        for (int k0 = 0; k0 < 64; k0 += 32) {
            bf16x8 af = *(const bf16x8*)&Gt[(wave * 16 + l15) * 72 + l4 * 8 + k0];
            #pragma unroll
            for (int j = 0; j < 4; ++j) {
                bf16x8 bfj = *(const bf16x8*)&xT[(j * 16 + l15) * 72 + l4 * 8 + k0];
                accY[j] = __builtin_amdgcn_mfma_f32_16x16x32_bf16(af, bfj, accY[j], 0, 0, 0);
            }
        }
        #pragma unroll
        for (int j = 0; j < 4; ++j) {
            #pragma unroll
            for (int rr = 0; rr < 4; ++rr) {
                int i = wave * 16 + l4 * 4 + rr;
                int p = j * 16 + l15;
                int t = q * QC + i;
                int l = rev ? (L_ - 1 - t) : t;
                float xv = bf2f(xT[p * 72 + i]);
                y[(size_t)(b * L_ + l) * DI + h * 64 + p] = f2bf(accY[j][rr] + Dh * xv);
            }
        }
    }
    {
        f32x4 accS[4];
        #pragma unroll
        for (int j = 0; j < 4; ++j) accS[j] = (f32x4){0.f, 0.f, 0.f, 0.f};
        #pragma unroll
        for (int k0 = 0; k0 < 64; k0 += 32) {
            bf16x8 af = *(const bf16x8*)&xT[(wave * 16 + l15) * 72 + l4 * 8 + k0];
            #pragma unroll
            for (int j = 0; j < 4; ++j) {
                bf16x8 bfj = *(const bf16x8*)&Btw[(j * 16 + l15) * 72 + l4 * 8 + k0];
                accS[j] = __builtin_amdgcn_mfma_f32_16x16x32_bf16(af, bfj, accS[j], 0, 0, 0);
            }
        }
        float* Sq = Sbuf + (size_t)bid * 4096;
        #pragma unroll
        for (int j = 0; j < 4; ++j) {
            #pragma unroll
            for (int rr = 0; rr < 4; ++rr) {
                int p = wave * 16 + l4 * 4 + rr;
                int n = j * 16 + l15;
                Sq[p * 64 + n] = accS[j][rr];
            }
        }
    }
}

// Parallel chain, both dirs (grid.z = dir)
__global__ void ssd_chain_kernel(float* __restrict__ Sb0, float* __restrict__ Sb1,
                                 const float* __restrict__ Edec) {
    const int dir = blockIdx.z;
    float* Sbuf = dir ? Sb1 : Sb0;
    const int bh = blockIdx.x;
    const int e = blockIdx.y * 256 + threadIdx.x;
    float* base = Sbuf + (size_t)bh * NC * 4096 + e;
    const float* Ep = Edec + dir * 1024 + bh * NC;
    float hst = 0.f;
    float tmp = base[0];
    #pragma unroll
    for (int q = 0; q < NC; ++q) {
        float nxt = (q + 1 < NC) ? base[(size_t)(q + 1) * 4096] : 0.f;
        float E = Ep[q];
        base[(size_t)q * 4096] = hst;
        hst = fmaf(E, hst, tmp);
        tmp = nxt;
    }
}

// ------- corr — MFMA, bf16 y RMW, both dirs: y += exp(sc_i)·(C_i · H^T) ------
__global__ __launch_bounds__(256) void ssd_corr_kernel(
        const unsigned short* __restrict__ xbcAll, const float* __restrict__ dtAll,
        const float* __restrict__ Al0, const float* __restrict__ Al1,
        const float* __restrict__ Sb0, const float* __restrict__ Sb1,
        unsigned short* __restrict__ y16) {
    const int dir = blockIdx.y;
    const int rev = dir;
    const unsigned short* xbc = xbcAll + (size_t)dir * NTOK * CONVCH;
    const float* dtb = dtAll + (size_t)dir * NTOK * NHM;
    const float* Sbuf = dir ? Sb1 : Sb0;
    unsigned short* y = y16 + (size_t)dir * NTOK * DI;

    const int bid = blockIdx.x;
    const int q = bid & (NC - 1);
    const int bh = bid / NC;
    const int b = bh >> 4, h = bh & 15;
    const int tid = threadIdx.x;
    const int wave = tid >> 6, lane = tid & 63;
    const int l15 = lane & 15, l4 = lane >> 4;

    __shared__ unsigned short Cb[64 * 72];
    __shared__ unsigned short Hb[64 * 72];
    __shared__ float sdt[QC], sc[QC];
    const float A = -__expf((dir ? Al1 : Al0)[h]);
    const int r = tid >> 2, qq = tid & 3;
    const float* Sq = Sbuf + (size_t)bid * 4096;

    #pragma unroll
    for (int j = 0; j < 4; ++j) {
        int qd = qq + j * 4;
        int t = q * QC + r;
        int l = rev ? (L_ - 1 - t) : t;
        const unsigned short* rowp = xbc + (size_t)(b * L_ + l) * CONVCH;
        *(ushort4v*)&Cb[r * 72 + qd * 4] = *(const ushort4v*)(rowp + 1088 + qd * 4);
        float4 hv = ((const float4*)Sq)[r * 16 + qd];
        ushort4v hh;
        hh[0] = f2bf(hv.x); hh[1] = f2bf(hv.y); hh[2] = f2bf(hv.z); hh[3] = f2bf(hv.w);
        *(ushort4v*)&Hb[r * 72 + qd * 4] = hh;
    }
    if (tid < QC) {
        int t = q * QC + tid;
        int l = rev ? (L_ - 1 - t) : t;
        sdt[tid] = dtb[(size_t)(b * L_ + l) * NHM + h];
    }
    __syncthreads();
    if (tid == 0) {
        float run = 0.f;
        for (int i = 0; i < QC; ++i) { run += A * sdt[i]; sc[i] = run; }
    }
    __syncthreads();

    f32x4 acc[4];
    #pragma unroll
    for (int j = 0; j < 4; ++j) acc[j] = (f32x4){0.f, 0.f, 0.f, 0.f};
    #pragma unroll
    for (int k0 = 0; k0 < 64; k0 += 32) {
        bf16x8 af = *(const bf16x8*)&Cb[(wave * 16 + l15) * 72 + l4 * 8 + k0];
        #pragma unroll
        for (int j = 0; j < 4; ++j) {
            bf16x8 bfj = *(const bf16x8*)&Hb[(j * 16 + l15) * 72 + l4 * 8 + k0];
            acc[j] = __builtin_amdgcn_mfma_f32_16x16x32_bf16(af, bfj, acc[j], 0, 0, 0);
        }
    }
    #pragma unroll
    for (int j = 0; j < 4; ++j) {
        #pragma unroll
        for (int rr = 0; rr < 4; ++rr) {
            int i = wave * 16 + l4 * 4 + rr;
            int p = j * 16 + l15;
            int t = q * QC + i;
            int l = rev ? (L_ - 1 - t) : t;
            float e = __expf(sc[i]);
            unsigned short* yp = &y[(size_t)(b * L_ + l) * DI + h * 64 + p];
            *yp = f2bf(bf2f(*yp) + e * acc[j][rr]);
        }
    }
}

// --- gate (silu(z) bf16) + RMSNorm -> bf16 combined buffer, both dirs -------
__global__ void gate_rmsnorm_kernel(const unsigned short* __restrict__ y16,
                                    const unsigned short* __restrict__ megaA,
                                    const float* __restrict__ nw0, const float* __restrict__ nw1,
                                    unsigned short* __restrict__ yb) {
    const int dir = blockIdx.y;
    const float* norm_w = dir ? nw1 : nw0;
    const int row = blockIdx.x;
    const int tid = threadIdx.x;
    const unsigned short* z = megaA + (size_t)row * QKVS + 1536 + dir * DINPROJ;
    const unsigned short* yr = y16 + (size_t)dir * NTOK * DI + (size_t)row * DI;
    float v[4];
    float ss = 0.f;
    #pragma unroll
    for (int i = 0; i < 4; ++i) {
        int c = i * 256 + tid;
        float g = siluf(bf2f(z[c]));
        v[i] = bf2f(yr[c]) * g;
        ss = fmaf(v[i], v[i], ss);
    }
    #pragma unroll
    for (int off = 32; off > 0; off >>= 1) ss += __shfl_xor(ss, off);
    __shared__ float red[4];
    int wid = tid >> 6, lane = tid & 63;
    if (lane == 0) red[wid] = ss;
    __syncthreads();
    ss = red[0] + red[1] + red[2] + red[3];
    float scale = rsqrtf(ss * (1.0f / 1024.0f) + 1e-5f);
    #pragma unroll
    for (int i = 0; i < 4; ++i) {
        int c = i * 256 + tid;
        yb[(size_t)row * 2048 + dir * 1024 + c] = f2bf(v[i] * scale * norm_w[c]);
    }
}

// ------ final: s = h+attn+msum+msum2 (split-K partials) ; LayerNorm(s) ------
__global__ void final_ln_kernel(const float* __restrict__ h, const float* __restrict__ attn,
                                const float* __restrict__ msum, const float* __restrict__ msum2,
                                const float* __restrict__ ln_w, const float* __restrict__ ln_b,
                                float* __restrict__ out) {
    const int row = blockIdx.x;
    const int tid = threadIdx.x;
    size_t base = (size_t)row * DM;
    float v[2];
    float sum = 0.f, sq = 0.f;
    #pragma unroll
    for (int i = 0; i < 2; ++i) {
        int c = i * 256 + tid;
        float s = h[base + c] + attn[base + c] + msum[base + c] + msum2[base + c];
        v[i] = s;
        sum += s;
        sq = fmaf(s, s, sq);
    }
    #pragma unroll
    for (int off = 32; off > 0; off >>= 1) {
        sum += __shfl_xor(sum, off);
        sq += __shfl_xor(sq, off);
    }
    __shared__ float rsum[4], rsq[4];
    int wid = tid >> 6, lane = tid & 63;
    if (lane == 0) { rsum[wid] = sum; rsq[wid] = sq; }
    __syncthreads();
    sum = rsum[0] + rsum[1] + rsum[2] + rsum[3];
    sq = rsq[0] + rsq[1] + rsq[2] + rsq[3];
    float mu = sum * (1.0f / DM);
    float var = sq * (1.0f / DM) - mu * mu;
    float rs = rsqrtf(var + 1e-5f);
    #pragma unroll
    for (int i = 0; i < 2; ++i) {
        int c = i * 256 + tid;
        out[base + c] = (v[i] - mu) * rs * ln_w[c] + ln_b[c];
    }
}

extern "C" void kernel_launch(void* const* d_in, const int* in_sizes, int n_in,
                              void* d_out, int out_size, void* d_ws, size_t ws_size,
                              hipStream_t stream) {
    const float* h          = (const float*)d_in[0];
    const float* attn_in_w  = (const float*)d_in[1];
    const float* attn_in_b  = (const float*)d_in[2];
    const float* attn_out_w = (const float*)d_in[3];
    const float* attn_out_b = (const float*)d_in[4];
    const float* ln_w       = (const float*)d_in[21];
    const float* ln_b       = (const float*)d_in[22];
    float* out = (float*)d_out;

    float* ws = (float*)d_ws;
    unsigned short* megaA = (unsigned short*)ws;
    unsigned short* bufXBC = (unsigned short*)(ws + 12124160);    // 2 dirs bf16
    float* bufDT   = ws + 12124160 + 4718592;
    float* bufY    = bufDT + 131072;        // as bf16: 2 dirs x 4096 x 1024
    float* bufATTN = bufY + 4194304;
    float* gateReg = bufATTN + 2097152;
    float* sReg    = gateReg + 4194304;
    float* bufEdec = sReg + 4194304;        // 2048 floats
    unsigned short* hB = (unsigned short*)(bufEdec + 2048);
    // overlays:
    unsigned short* wBIG   = (unsigned short*)gateReg;            // early
    unsigned short* wAOUT  = wBIG + (size_t)QKVS * DM;
    unsigned short* gatedB = (unsigned short*)gateReg;            // late (after corr)
    unsigned short* actB   = (unsigned short*)sReg;               // early
    float* bufS0           = sReg;                                // scan S dir0
    float* bufS1           = gateReg;                             // scan S dir1 (wBIG dead)
    unsigned short* wC     = (unsigned short*)sReg;               // late
    unsigned short* y16    = (unsigned short*)bufY;               // 2-dir bf16 y
    float* msum            = bufY;                                // outproj split-K partial 0
    float* msum2           = bufY + (size_t)NTOK * DM;            // partial 1 (y16 dead)

    const float* inproj_fwd = (const float*)d_in[5];
    const float* inproj_bwd = (const float*)d_in[13];

    dim3 blk(256);

    // 0) fused cvt
    cvt_all_kernel<<<dim3(S4 / 256), blk, 0, stream>>>(
        h, hB, attn_in_w, wBIG, attn_out_w, wAOUT,
        inproj_fwd, wBIG + (size_t)1536 * DM, inproj_bwd, wBIG + (size_t)3728 * DM);

    // 1) mega projection GEMM (XCD-chunked swizzle; proven structure +
    //    2-way swizzle + occupancy cap 128 regs)
    gemm_mfma_staged<128, true, true, false><<<dim3(8 * 6 * (NTOK / 128)), blk, 0, stream>>>(
        hB, wBIG, attn_in_b, 1536, megaA, NTOK, QKVS, DM);

    // 2) attention
    attn_mfma_kernel<<<dim3(B_ * NHA * (L_ / 64)), blk, 0, stream>>>(megaA, actB);
    // 3) attn_out
    gemm_mfma_staged<64, false, false, false><<<dim3(DM / 64, NTOK / 128), blk, 0, stream>>>(
        actB, wAOUT, attn_out_b, DM, bufATTN, NTOK, DM, DM);

    // 4) dt + conv (both dirs each)
    dt_exact_kernel<<<dim3(NTOK), blk, 0, stream>>>(
        h, inproj_fwd + (size_t)(DINPROJ - NHM) * DM, (const float*)d_in[8],
        inproj_bwd + (size_t)(DINPROJ - NHM) * DM, (const float*)d_in[16], bufDT);
    conv_silu_kernel<<<dim3(((NTOK / 4) * (CONVCH / 4) + 255) / 256, 2), blk, 0, stream>>>(
        megaA, (const float*)d_in[6], (const float*)d_in[7],
        (const float*)d_in[14], (const float*)d_in[15], bufXBC);

    // 5) scan: both dirs per dispatch
    ssd_chunk_kernel<<<dim3(B_ * NHM * NC, 2), blk, 0, stream>>>(
        bufXBC, bufDT, (const float*)d_in[9], (const float*)d_in[10],
        (const float*)d_in[17], (const float*)d_in[18], y16, bufS0, bufS1, bufEdec);
    ssd_chain_kernel<<<dim3(B_ * NHM, 16, 2), blk, 0, stream>>>(bufS0, bufS1, bufEdec);
    ssd_corr_kernel<<<dim3(B_ * NHM * NC, 2), blk, 0, stream>>>(
        bufXBC, bufDT, (const float*)d_in[9], (const float*)d_in[17], bufS0, bufS1, y16);
    gate_rmsnorm_kernel<<<dim3(NTOK, 2), blk, 0, stream>>>(
        y16, megaA, (const float*)d_in[11], (const float*)d_in[19], gatedB);

    // 6) Combined outproj — split-K=2 (grid.z), partials summed in final_ln
    cvt_outproj_kernel<<<dim3((2 * DM * DI / 8 + 255) / 256), blk, 0, stream>>>(
        (const float*)d_in[12], (const float*)d_in[20], wC);
    gemm_mfma_staged<64, false, false, true><<<dim3(DM / 64, NTOK / 128, 2), blk, 0, stream>>>(
        gatedB, wC, nullptr, 0, msum, NTOK, DM, 2048);

    final_ln_kernel<<<dim3(NTOK), blk, 0, stream>>>(
        h, bufATTN, msum, msum2, ln_w, ln_b, out);
}

// Round 4
// 235.048 us; speedup vs baseline: 1.1366x; 1.1366x over previous
//
#include <hip/hip_runtime.h>
#include <math.h>
#include <stdint.h>

#define B_ 4
#define L_ 1024
#define DM 512
#define NHA 32
#define HD 16
#define DI 1024
#define DSTATE 64
#define HDIM_ 64
#define NHM 16
#define DCONV 4
#define CONVCH 1152
#define DINPROJ 2192
#define NTOK (B_*L_)
#define QC 64
#define NC (L_/QC)
#define QKVS 5920            // mega zxbcdt row stride: 1536 + 2192 + 2192

typedef __bf16 bf16x8 __attribute__((ext_vector_type(8)));
typedef float f32x4 __attribute__((ext_vector_type(4)));
typedef unsigned short ushort8 __attribute__((ext_vector_type(8)));
typedef unsigned short ushort4v __attribute__((ext_vector_type(4)));
typedef __fp16 fp16x2 __attribute__((ext_vector_type(2)));
typedef _Float16 f16x4 __attribute__((ext_vector_type(4)));
typedef _Float16 f16x8 __attribute__((ext_vector_type(8)));

__device__ __forceinline__ float siluf(float x) {
    return x / (1.0f + __expf(-x));
}

__device__ __forceinline__ unsigned short f2bf(float f) {
    unsigned u = __float_as_uint(f);
    unsigned r = (u + 0x7FFFu + ((u >> 16) & 1u)) >> 16;
    return (unsigned short)r;
}

__device__ __forceinline__ float bf2f(unsigned short u) {
    return __uint_as_float((unsigned)u << 16);
}

__device__ __forceinline__ void cvt8(const float* src, unsigned short* dst) {
    float4 a = ((const float4*)src)[0];
    float4 b = ((const float4*)src)[1];
    ushort8 o;
    o[0] = f2bf(a.x); o[1] = f2bf(a.y); o[2] = f2bf(a.z); o[3] = f2bf(a.w);
    o[4] = f2bf(b.x); o[5] = f2bf(b.y); o[6] = f2bf(b.z); o[7] = f2bf(b.w);
    *(ushort8*)dst = o;
}

// async global->LDS 16B
__device__ __forceinline__ void gload16(const void* g, void* l) {
    auto gp = reinterpret_cast<const __attribute__((address_space(1))) unsigned int*>(
        reinterpret_cast<uintptr_t>(g));
    auto lp = reinterpret_cast<__attribute__((address_space(3))) unsigned int*>(
        reinterpret_cast<uintptr_t>(l));
    __builtin_amdgcn_global_load_lds(gp, lp, 16, 0, 0);
}

// LDS chunk swizzle: slot = chunk ^ sw(row). Old (row&3) left rows {0,4,8,12}
// on the same 4 banks (4-way conflict, 3.1M counter hits); (row^(row>>2))&3
// makes same-parity rows hit distinct slots -> 2-way aliasing (free, m136).
__device__ __forceinline__ int swz3(int row) {
    return (row ^ (row >> 2)) & 3;
}

// ---- fused f32->bf16: h + qkv_w + attn_out_w + inproj_fwd + inproj_bwd ----
#define S0 262144
#define S1 (S0 + 98304)
#define S2 (S1 + 32768)
#define S3 (S2 + 140288)
#define S4 (S3 + 140288)
__global__ void cvt_all_kernel(const float* __restrict__ h, unsigned short* __restrict__ hB,
                               const float* __restrict__ w1, unsigned short* __restrict__ d1,
                               const float* __restrict__ w2, unsigned short* __restrict__ d2,
                               const float* __restrict__ w3, unsigned short* __restrict__ d3,
                               const float* __restrict__ w4, unsigned short* __restrict__ d4) {
    int i = blockIdx.x * blockDim.x + threadIdx.x;
    const float* src; unsigned short* dst; int off;
    if (i < S0)      { src = h;  dst = hB; off = i; }
    else if (i < S1) { src = w1; dst = d1; off = i - S0; }
    else if (i < S2) { src = w2; dst = d2; off = i - S1; }
    else if (i < S3) { src = w3; dst = d3; off = i - S2; }
    else             { src = w4; dst = d4; off = i - S3; }
    cvt8(src + (size_t)off * 8, dst + (size_t)off * 8);
}

// ---- outproj concat cvt: fwd+bwd into [512][2048] bf16, one launch ----
__global__ void cvt_outproj_kernel(const float* __restrict__ fw, const float* __restrict__ bw,
                                   unsigned short* __restrict__ dst) {
    int i = blockIdx.x * blockDim.x + threadIdx.x;
    const int n8 = DM * DI / 8;
    int half = i >= n8;
    int off = half ? i - n8 : i;
    const float* src = half ? bw : fw;
    int e = off * 8;
    int r = e / DI, c = e % DI;
    cvt8(src + e, dst + (size_t)r * 2048 + half * 1024 + c);
}

// ---------- Staged MFMA GEMM: C[M,N] = Ab[M,K] @ Wb[N,K]^T (+bias cols<biasN)
// launch_bounds(256,4): cap unified VGPR+AGPR at 128 -> 4 blocks/CU resident
// (was 132 regs -> 2 blocks/CU, the latency-bound occupancy ceiling).
// SPLITK: grid.z = 2 halves of K, each writes its own f32 C buffer
// (summed downstream) -> doubles resident blocks for skinny-N deep-K GEMMs.
template <int BN, bool OBF16, bool SWZ, bool SPLITK>
__global__ __launch_bounds__(256, 4) void gemm_mfma_staged(
        const unsigned short* __restrict__ Ab, const unsigned short* __restrict__ Wb,
        const float* __restrict__ bias, int biasN, void* __restrict__ Cout,
        int M, int N, int K) {
    constexpr int BM = 128, BK = 32;
    constexpr int NF = BN / 32;
    constexpr int BLOADS = BN / 64;
    __shared__ unsigned short As[2][BM * BK];
    __shared__ unsigned short Bs[2][BN * BK];

    const int tid = threadIdx.x;
    const int wave = tid >> 6, lane = tid & 63;
    const int l15 = lane & 15, g = lane >> 4;
    const int wm = wave >> 1, wn = wave & 1;
    int m0, n0;
    if constexpr (SWZ) {
        int d = blockIdx.x;
        int xcd = d & 7, jj = d >> 3;
        n0 = (xcd * 6 + jj % 6) * BN;
        m0 = (jj / 6) * BM;
    } else {
        m0 = blockIdx.y * BM;
        n0 = blockIdx.x * BN;
    }

    f32x4 acc[4][NF];
    #pragma unroll
    for (int mi = 0; mi < 4; ++mi)
        #pragma unroll
        for (int nj = 0; nj < NF; ++nj) acc[mi][nj] = (f32x4){0.f, 0.f, 0.f, 0.f};

    auto stage = [&](int bufi, int k0) {
        #pragma unroll
        for (int i = 0; i < 2; ++i) {
            int c = (wave * 2 + i) * 64 + lane;
            int row = c >> 2;
            int kc = ((c & 3) ^ swz3(row)) * 8;      // pre-swizzled source
            gload16(Ab + (size_t)(m0 + row) * K + k0 + kc,
                    &As[bufi][(wave * 2 + i) * 64 * 8]);
        }
        #pragma unroll
        for (int i = 0; i < BLOADS; ++i) {
            int c = (wave * BLOADS + i) * 64 + lane;
            int row = c >> 2;
            int kc = ((c & 3) ^ swz3(row)) * 8;
            int rn = n0 + row; if (rn >= N) rn = N - 1;
            gload16(Wb + (size_t)rn * K + k0 + kc,
                    &Bs[bufi][(wave * BLOADS + i) * 64 * 8]);
        }
    };

    const int kBeg = SPLITK ? blockIdx.z * (K >> 1) : 0;
    const int kLen = SPLITK ? (K >> 1) : K;

    int cur = 0;
    stage(0, kBeg);
    __syncthreads();
    for (int kk = 0; kk < kLen; kk += BK) {
        if (kk + BK < kLen) stage(cur ^ 1, kBeg + kk + BK);
        const unsigned short* Ac = As[cur];
        const unsigned short* Bc = Bs[cur];
        bf16x8 af[4];
        #pragma unroll
        for (int mi = 0; mi < 4; ++mi) {
            int ar = wm * 64 + mi * 16 + l15;
            af[mi] = *(const bf16x8*)(Ac + ar * BK + ((g ^ swz3(ar)) * 8));
        }
        bf16x8 bfr[NF];
        #pragma unroll
        for (int nj = 0; nj < NF; ++nj) {
            int br = wn * (BN / 2) + nj * 16 + l15;
            bfr[nj] = *(const bf16x8*)(Bc + br * BK + ((g ^ swz3(br)) * 8));
        }
        #pragma unroll
        for (int mi = 0; mi < 4; ++mi)
            #pragma unroll
            for (int nj = 0; nj < NF; ++nj)
                acc[mi][nj] = __builtin_amdgcn_mfma_f32_16x16x32_bf16(af[mi], bfr[nj], acc[mi][nj], 0, 0, 0);
        __syncthreads();
        cur ^= 1;
    }

    float* CoutF = (float*)Cout;
    if constexpr (SPLITK) CoutF += (size_t)blockIdx.z * M * N;

    #pragma unroll
    for (int mi = 0; mi < 4; ++mi) {
        int rbase = m0 + wm * 64 + mi * 16 + g * 4;
        #pragma unroll
        for (int nj = 0; nj < NF; ++nj) {
            int col = n0 + wn * (BN / 2) + nj * 16 + l15;
            if (col < N) {
                float bv = (bias && col < biasN && (!SPLITK || blockIdx.z == 0)) ? bias[col] : 0.f;
                #pragma unroll
                for (int r = 0; r < 4; ++r) {
                    float v = acc[mi][nj][r] + bv;
                    if constexpr (OBF16)
                        ((unsigned short*)Cout)[(size_t)(rbase + r) * N + col] = f2bf(v);
                    else
                        CoutF[(size_t)(rbase + r) * N + col] = v;
                }
            }
        }
    }
}

// ---------------- MFMA Attention (flash, d=16, fp16 mfma) ----------------
#define KP 24
#define VP 132
__global__ __launch_bounds__(256) void attn_mfma_kernel(const unsigned short* __restrict__ qkv,
                                                        unsigned short* __restrict__ ob) {
    const int n = blockIdx.x;
    const int xcd = n & 7;
    const int j = n >> 3;
    const int bh = ((j >> 4) << 3) + xcd;
    const int qt = j & 15;
    const int h = bh & 31;
    const int b = bh >> 5;
    const int tid = threadIdx.x;
    const int wave = tid >> 6, lane = tid & 63;
    const int l15 = lane & 15, g = lane >> 4;

    __shared__ _Float16 Ksm[128 * KP];
    __shared__ _Float16 VsmT[16 * VP];

    const unsigned short* base = qkv + (size_t)b * L_ * QKVS;
    const int qrow = qt * 64 + wave * 16 + l15;

    f16x4 qf;
    {
        ushort4v qv = *(const ushort4v*)(base + (size_t)qrow * QKVS + h * 16 + g * 4);
        fp16x2 qa = __builtin_amdgcn_cvt_pkrtz(bf2f(qv[0]) * 0.25f, bf2f(qv[1]) * 0.25f);
        fp16x2 qb = __builtin_amdgcn_cvt_pkrtz(bf2f(qv[2]) * 0.25f, bf2f(qv[3]) * 0.25f);
        qf[0] = (_Float16)qa[0]; qf[1] = (_Float16)qa[1];
        qf[2] = (_Float16)qb[0]; qf[3] = (_Float16)qb[1];
    }
    f32x4 yacc = (f32x4){0.f, 0.f, 0.f, 0.f};
    float s = 0.f;

    const int sk = tid >> 1;
    const int sd = (tid & 1) * 8;

    for (int c0 = 0; c0 < L_; c0 += 128) {
        {
            ushort8 ka = *(const ushort8*)(base + (size_t)(c0 + sk) * QKVS + 512 + h * 16 + sd);
            fp16x2 k0 = __builtin_amdgcn_cvt_pkrtz(bf2f(ka[0]), bf2f(ka[1]));
            fp16x2 k1 = __builtin_amdgcn_cvt_pkrtz(bf2f(ka[2]), bf2f(ka[3]));
            fp16x2 k2 = __builtin_amdgcn_cvt_pkrtz(bf2f(ka[4]), bf2f(ka[5]));
            fp16x2 k3 = __builtin_amdgcn_cvt_pkrtz(bf2f(ka[6]), bf2f(ka[7]));
            f16x8 kv;
            kv[0] = (_Float16)k0[0]; kv[1] = (_Float16)k0[1];
            kv[2] = (_Float16)k1[0]; kv[3] = (_Float16)k1[1];
            kv[4] = (_Float16)k2[0]; kv[5] = (_Float16)k2[1];
            kv[6] = (_Float16)k3[0]; kv[7] = (_Float16)k3[1];
            *(f16x8*)(&Ksm[sk * KP + sd]) = kv;
            ushort8 va = *(const ushort8*)(base + (size_t)(c0 + sk) * QKVS + 1024 + h * 16 + sd);
            #pragma unroll
            for (int jj = 0; jj < 8; ++jj)
                VsmT[(sd + jj) * VP + sk] = (_Float16)bf2f(va[jj]);
        }
        __syncthreads();
        #pragma unroll
        for (int half = 0; half < 2; ++half) {
            f32x4 st[4];
            #pragma unroll
            for (int ks = 0; ks < 4; ++ks) {
                f16x4 kf = *(const f16x4*)(&Ksm[((half * 4 + ks) * 16 + l15) * KP + g * 4]);
                st[ks] = __builtin_amdgcn_mfma_f32_16x16x16f16(kf, qf, (f32x4){0.f,0.f,0.f,0.f}, 0, 0, 0);
            }
            float p[16];
            float cs = 0.f;
            #pragma unroll
            for (int ks = 0; ks < 4; ++ks) {
                #pragma unroll
                for (int r = 0; r < 4; ++r) {
                    p[ks * 4 + r] = __expf(st[ks][r]);
                    cs += p[ks * 4 + r];
                }
            }
            cs += __shfl_xor(cs, 16);
            cs += __shfl_xor(cs, 32);
            s += cs;
            #pragma unroll
            for (int ks = 0; ks < 4; ++ks) {
                fp16x2 plo = __builtin_amdgcn_cvt_pkrtz(p[ks*4+0], p[ks*4+1]);
                fp16x2 phi = __builtin_amdgcn_cvt_pkrtz(p[ks*4+2], p[ks*4+3]);
                f16x4 pf;
                pf[0] = (_Float16)plo[0]; pf[1] = (_Float16)plo[1];
                pf[2] = (_Float16)phi[0]; pf[3] = (_Float16)phi[1];
                f16x4 vf = *(const f16x4*)(&VsmT[l15 * VP + (half * 4 + ks) * 16 + g * 4]);
                yacc = __builtin_amdgcn_mfma_f32_16x16x16f16(vf, pf, yacc, 0, 0, 0);
            }
        }
        __syncthreads();
    }
    float inv = 1.f / s;
    ushort4v o;
    o[0] = f2bf(yacc[0] * inv);
    o[1] = f2bf(yacc[1] * inv);
    o[2] = f2bf(yacc[2] * inv);
    o[3] = f2bf(yacc[3] * inv);
    *(ushort4v*)(ob + (size_t)(b * L_ + qrow) * 512 + h * 16 + g * 4) = o;
}

// -- Causal depthwise conv (+bias+silu), bf16 in/out, both dirs (grid.y) -----
// Round-0 version: 1 output/thread, 9216 blocks -> TLP hides strided latency
// (round-3's 4-outputs/thread cut TLP 4x and doubled duration; reverted).
__global__ void conv_silu_kernel(const unsigned short* __restrict__ megaA,
                                 const float* __restrict__ cw0, const float* __restrict__ cb0,
                                 const float* __restrict__ cw1, const float* __restrict__ cb1,
                                 unsigned short* __restrict__ out) {
    const int rev = blockIdx.y;
    const float* conv_w = rev ? cw1 : cw0;
    const float* conv_b = rev ? cb1 : cb0;
    int idx = blockIdx.x * blockDim.x + threadIdx.x;
    if (idx >= NTOK * (CONVCH / 4)) return;
    int c4 = (idx % (CONVCH / 4)) * 4;
    int bl = idx / (CONVCH / 4);
    int l = bl % L_;
    int b = bl / L_;
    const unsigned short* src = megaA + (size_t)b * L_ * QKVS + 1536 + rev * DINPROJ + 1024 + c4;
    float4 w0 = *(const float4*)(conv_w + (c4 + 0) * 4);
    float4 w1 = *(const float4*)(conv_w + (c4 + 1) * 4);
    float4 w2 = *(const float4*)(conv_w + (c4 + 2) * 4);
    float4 w3 = *(const float4*)(conv_w + (c4 + 3) * 4);
    float4 acc = *(const float4*)(conv_b + c4);
    const float wt[4][4] = {{w0.x, w0.y, w0.z, w0.w}, {w1.x, w1.y, w1.z, w1.w},
                            {w2.x, w2.y, w2.z, w2.w}, {w3.x, w3.y, w3.z, w3.w}};
    #pragma unroll
    for (int j = 0; j < 4; ++j) {
        int ll = rev ? (l + 3 - j) : (l - 3 + j);
        if (ll >= 0 && ll < L_) {
            ushort4v x = *(const ushort4v*)(src + (size_t)ll * QKVS);
            acc.x = fmaf(wt[0][j], bf2f(x[0]), acc.x);
            acc.y = fmaf(wt[1][j], bf2f(x[1]), acc.y);
            acc.z = fmaf(wt[2][j], bf2f(x[2]), acc.z);
            acc.w = fmaf(wt[3][j], bf2f(x[3]), acc.w);
        }
    }
    ushort4v o;
    o[0] = f2bf(siluf(acc.x)); o[1] = f2bf(siluf(acc.y));
    o[2] = f2bf(siluf(acc.z)); o[3] = f2bf(siluf(acc.w));
    *(ushort4v*)(out + (size_t)rev * NTOK * CONVCH + (size_t)bl * CONVCH + c4) = o;
}

// ------------- exact fp32 dt, BOTH directions per block (h read once) -------
__global__ void dt_exact_kernel(const float* __restrict__ h,
                                const float* __restrict__ wdt0, const float* __restrict__ bias0,
                                const float* __restrict__ wdt1, const float* __restrict__ bias1,
                                float* __restrict__ dt) {
    const int row = blockIdx.x;
    const int tid = threadIdx.x;
    const int g = tid >> 4, j = tid & 15;
    const float* hr = h + (size_t)row * DM;
    const float* wr0 = wdt0 + (size_t)g * DM;
    const float* wr1 = wdt1 + (size_t)g * DM;
    float s0 = 0.f, s1 = 0.f;
    #pragma unroll 8
    for (int t = 0; t < 32; ++t) {
        int k = j + t * 16;
        float hv = hr[k];
        s0 = fmaf(hv, wr0[k], s0);
        s1 = fmaf(hv, wr1[k], s1);
    }
    s0 += __shfl_xor(s0, 1); s0 += __shfl_xor(s0, 2);
    s0 += __shfl_xor(s0, 4); s0 += __shfl_xor(s0, 8);
    s1 += __shfl_xor(s1, 1); s1 += __shfl_xor(s1, 2);
    s1 += __shfl_xor(s1, 4); s1 += __shfl_xor(s1, 8);
    if (j == 0) {
        float v0 = s0 + bias0[g];
        float v1 = s1 + bias1[g];
        dt[(size_t)row * NHM + g] = (v0 > 20.f) ? v0 : log1pf(__expf(v0));
        dt[(size_t)NTOK * NHM + (size_t)row * NHM + g] = (v1 > 20.f) ? v1 : log1pf(__expf(v1));
    }
}

// ======= Chunked SSD — MFMA, bf16 xbc & y, both dirs (grid.y = dir) =======
__global__ __launch_bounds__(256) void ssd_chunk_kernel(
        const unsigned short* __restrict__ xbcAll, const float* __restrict__ dtAll,
        const float* __restrict__ Al0, const float* __restrict__ Dp0,
        const float* __restrict__ Al1, const float* __restrict__ Dp1,
        unsigned short* __restrict__ y16, float* __restrict__ Sb0, float* __restrict__ Sb1,
        float* __restrict__ Edec) {
    const int dir = blockIdx.y;
    const int rev = dir;
    const unsigned short* xbc = xbcAll + (size_t)dir * NTOK * CONVCH;
    const float* dtb = dtAll + (size_t)dir * NTOK * NHM;
    float* Sbuf = dir ? Sb1 : Sb0;
    unsigned short* y = y16 + (size_t)dir * NTOK * DI;

    const int bid = blockIdx.x;
    const int q = bid & (NC - 1);
    const int bh = bid / NC;
    const int b = bh >> 4, h = bh & 15;
    const int tid = threadIdx.x;
    const int wave = tid >> 6, lane = tid & 63;
    const int l15 = lane & 15, l4 = lane >> 4;

    __shared__ unsigned short Bn[64 * 72];
    __shared__ unsigned short Cn[64 * 72];
    __shared__ unsigned short Btw[64 * 72];
    __shared__ unsigned short Gt[64 * 72];
    __shared__ unsigned short xT[64 * 72];
    __shared__ float sdt[QC], sc[QC], wsv[QC];

    const float A = -__expf((dir ? Al1 : Al0)[h]);
    const float Dh = (dir ? Dp1 : Dp0)[h];
    const int r = tid >> 2, qq = tid & 3;

    #pragma unroll
    for (int j = 0; j < 4; ++j) {
        int qd = qq + j * 4;
        int t = q * QC + r;
        int l = rev ? (L_ - 1 - t) : t;
        const unsigned short* rowp = xbc + (size_t)(b * L_ + l) * CONVCH;
        *(ushort4v*)&Bn[r * 72 + qd * 4] = *(const ushort4v*)(rowp + 1024 + qd * 4);
        *(ushort4v*)&Cn[r * 72 + qd * 4] = *(const ushort4v*)(rowp + 1088 + qd * 4);
    }
    if (tid < QC) {
        int t = q * QC + tid;
        int l = rev ? (L_ - 1 - t) : t;
        sdt[tid] = dtb[(size_t)(b * L_ + l) * NHM + h];
    }
    __syncthreads();
    if (tid == 0) {
        float run = 0.f;
        for (int i = 0; i < QC; ++i) { run += A * sdt[i]; sc[i] = run; }
    }
    __syncthreads();
    if (tid < QC) wsv[tid] = sdt[tid] * __expf(sc[QC - 1] - sc[tid]);
    if (tid == 0) Edec[dir * 1024 + bid] = __expf(sc[QC - 1]);
    __syncthreads();

    {
        int n = tid >> 2, s0 = (tid & 3) * 16;
        ushort8 o0, o1;
        #pragma unroll
        for (int k = 0; k < 8; ++k) {
            o0[k] = f2bf(bf2f(Bn[(s0 + k) * 72 + n]) * wsv[s0 + k]);
            o1[k] = f2bf(bf2f(Bn[(s0 + 8 + k) * 72 + n]) * wsv[s0 + 8 + k]);
        }
        *(ushort8*)&Btw[n * 72 + s0] = o0;
        *(ushort8*)&Btw[n * 72 + s0 + 8] = o1;
    }
    #pragma unroll
    for (int j = 0; j < 4; ++j) {
        int qd = qq + j * 4;
        int t = q * QC + r;
        int l = rev ? (L_ - 1 - t) : t;
        const unsigned short* rowp = xbc + (size_t)(b * L_ + l) * CONVCH + h * 64;
        ushort4v xv = *(const ushort4v*)(rowp + qd * 4);
        xT[(qd * 4 + 0) * 72 + r] = xv[0];
        xT[(qd * 4 + 1) * 72 + r] = xv[1];
        xT[(qd * 4 + 2) * 72 + r] = xv[2];
        xT[(qd * 4 + 3) * 72 + r] = xv[3];
    }
    __syncthreads();

    f32x4 accG[4];
    #pragma unroll
    for (int j = 0; j < 4; ++j) accG[j] = (f32x4){0.f, 0.f, 0.f, 0.f};
    #pragma unroll
    for (int k0 = 0; k0 < 64; k0 += 32) {
        bf16x8 af = *(const bf16x8*)&Bn[(wave * 16 + l15) * 72 + l4 * 8 + k0];
        #pragma unroll
        for (int j = 0; j < 4; ++j) {
            bf16x8 bfj = *(const bf16x8*)&Cn[(j * 16 + l15) * 72 + l4 * 8 + k0];
            accG[j] = __builtin_amdgcn_mfma_f32_16x16x32_bf16(af, bfj, accG[j], 0, 0, 0);
        }
    }
    #pragma unroll
    for (int j = 0; j < 4; ++j) {
        #pragma unroll
        for (int rr = 0; rr < 4; ++rr) {
            int s = wave * 16 + l4 * 4 + rr;
            int i = j * 16 + l15;
            float g = (s <= i) ? accG[j][rr] * sdt[s] * __expf(sc[i] - sc[s]) : 0.f;
            Gt[i * 72 + s] = f2bf(g);
        }
    }
    __syncthreads();

    {
        f32x4 accY[4];
        #pragma unroll
        for (int j = 0; j < 4; ++j) accY[j] = (f32x4){0.f, 0.f, 0.f, 0.f};
        #pragma unroll
        for (int k0 = 0; k0 < 64; k0 += 32) {
            bf16x8 af = *(const bf16x8*)&Gt[(wave * 16 + l15) * 72 + l4 * 8 + k0];
            #pragma unroll
            for (int j = 0; j < 4; ++j) {
                bf16x8 bfj = *(const bf16x8*)&xT[(j * 16 + l15) * 72 + l4 * 8 + k0];
                accY[j] = __builtin_amdgcn_mfma_f32_16x16x32_bf16(af, bfj, accY[j], 0, 0, 0);
            }
        }
        #pragma unroll
        for (int j = 0; j < 4; ++j) {
            #pragma unroll
            for (int rr = 0; rr < 4; ++rr) {
                int i = wave * 16 + l4 * 4 + rr;
                int p = j * 16 + l15;
                int t = q * QC + i;
                int l = rev ? (L_ - 1 - t) : t;
                float xv = bf2f(xT[p * 72 + i]);
                y[(size_t)(b * L_ + l) * DI + h * 64 + p] = f2bf(accY[j][rr] + Dh * xv);
            }
        }
    }
    {
        f32x4 accS[4];
        #pragma unroll
        for (int j = 0; j < 4; ++j) accS[j] = (f32x4){0.f, 0.f, 0.f, 0.f};
        #pragma unroll
        for (int k0 = 0; k0 < 64; k0 += 32) {
            bf16x8 af = *(const bf16x8*)&xT[(wave * 16 + l15) * 72 + l4 * 8 + k0];
            #pragma unroll
            for (int j = 0; j < 4; ++j) {
                bf16x8 bfj = *(const bf16x8*)&Btw[(j * 16 + l15) * 72 + l4 * 8 + k0];
                accS[j] = __builtin_amdgcn_mfma_f32_16x16x32_bf16(af, bfj, accS[j], 0, 0, 0);
            }
        }
        float* Sq = Sbuf + (size_t)bid * 4096;
        #pragma unroll
        for (int j = 0; j < 4; ++j) {
            #pragma unroll
            for (int rr = 0; rr < 4; ++rr) {
                int p = wave * 16 + l4 * 4 + rr;
                int n = j * 16 + l15;
                Sq[p * 64 + n] = accS[j][rr];
            }
        }
    }
}

// Parallel chain, both dirs (grid.z = dir)
__global__ void ssd_chain_kernel(float* __restrict__ Sb0, float* __restrict__ Sb1,
                                 const float* __restrict__ Edec) {
    const int dir = blockIdx.z;
    float* Sbuf = dir ? Sb1 : Sb0;
    const int bh = blockIdx.x;
    const int e = blockIdx.y * 256 + threadIdx.x;
    float* base = Sbuf + (size_t)bh * NC * 4096 + e;
    const float* Ep = Edec + dir * 1024 + bh * NC;
    float hst = 0.f;
    float tmp = base[0];
    #pragma unroll
    for (int q = 0; q < NC; ++q) {
        float nxt = (q + 1 < NC) ? base[(size_t)(q + 1) * 4096] : 0.f;
        float E = Ep[q];
        base[(size_t)q * 4096] = hst;
        hst = fmaf(E, hst, tmp);
        tmp = nxt;
    }
}

// ------- corr — MFMA, bf16 y RMW, both dirs: y += exp(sc_i)·(C_i · H^T) ------
__global__ __launch_bounds__(256) void ssd_corr_kernel(
        const unsigned short* __restrict__ xbcAll, const float* __restrict__ dtAll,
        const float* __restrict__ Al0, const float* __restrict__ Al1,
        const float* __restrict__ Sb0, const float* __restrict__ Sb1,
        unsigned short* __restrict__ y16) {
    const int dir = blockIdx.y;
    const int rev = dir;
    const unsigned short* xbc = xbcAll + (size_t)dir * NTOK * CONVCH;
    const float* dtb = dtAll + (size_t)dir * NTOK * NHM;
    const float* Sbuf = dir ? Sb1 : Sb0;
    unsigned short* y = y16 + (size_t)dir * NTOK * DI;

    const int bid = blockIdx.x;
    const int q = bid & (NC - 1);
    const int bh = bid / NC;
    const int b = bh >> 4, h = bh & 15;
    const int tid = threadIdx.x;
    const int wave = tid >> 6, lane = tid & 63;
    const int l15 = lane & 15, l4 = lane >> 4;

    __shared__ unsigned short Cb[64 * 72];
    __shared__ unsigned short Hb[64 * 72];
    __shared__ float sdt[QC], sc[QC];
    const float A = -__expf((dir ? Al1 : Al0)[h]);
    const int r = tid >> 2, qq = tid & 3;
    const float* Sq = Sbuf + (size_t)bid * 4096;

    #pragma unroll
    for (int j = 0; j < 4; ++j) {
        int qd = qq + j * 4;
        int t = q * QC + r;
        int l = rev ? (L_ - 1 - t) : t;
        const unsigned short* rowp = xbc + (size_t)(b * L_ + l) * CONVCH;
        *(ushort4v*)&Cb[r * 72 + qd * 4] = *(const ushort4v*)(rowp + 1088 + qd * 4);
        float4 hv = ((const float4*)Sq)[r * 16 + qd];
        ushort4v hh;
        hh[0] = f2bf(hv.x); hh[1] = f2bf(hv.y); hh[2] = f2bf(hv.z); hh[3] = f2bf(hv.w);
        *(ushort4v*)&Hb[r * 72 + qd * 4] = hh;
    }
    if (tid < QC) {
        int t = q * QC + tid;
        int l = rev ? (L_ - 1 - t) : t;
        sdt[tid] = dtb[(size_t)(b * L_ + l) * NHM + h];
    }
    __syncthreads();
    if (tid == 0) {
        float run = 0.f;
        for (int i = 0; i < QC; ++i) { run += A * sdt[i]; sc[i] = run; }
    }
    __syncthreads();

    f32x4 acc[4];
    #pragma unroll
    for (int j = 0; j < 4; ++j) acc[j] = (f32x4){0.f, 0.f, 0.f, 0.f};
    #pragma unroll
    for (int k0 = 0; k0 < 64; k0 += 32) {
        bf16x8 af = *(const bf16x8*)&Cb[(wave * 16 + l15) * 72 + l4 * 8 + k0];
        #pragma unroll
        for (int j = 0; j < 4; ++j) {
            bf16x8 bfj = *(const bf16x8*)&Hb[(j * 16 + l15) * 72 + l4 * 8 + k0];
            acc[j] = __builtin_amdgcn_mfma_f32_16x16x32_bf16(af, bfj, acc[j], 0, 0, 0);
        }
    }
    #pragma unroll
    for (int j = 0; j < 4; ++j) {
        #pragma unroll
        for (int rr = 0; rr < 4; ++rr) {
            int i = wave * 16 + l4 * 4 + rr;
            int p = j * 16 + l15;
            int t = q * QC + i;
            int l = rev ? (L_ - 1 - t) : t;
            float e = __expf(sc[i]);
            unsigned short* yp = &y[(size_t)(b * L_ + l) * DI + h * 64 + p];
            *yp = f2bf(bf2f(*yp) + e * acc[j][rr]);
        }
    }
}

// --- gate (silu(z) bf16) + RMSNorm -> bf16 combined buffer, both dirs -------
__global__ void gate_rmsnorm_kernel(const unsigned short* __restrict__ y16,
                                    const unsigned short* __restrict__ megaA,
                                    const float* __restrict__ nw0, const float* __restrict__ nw1,
                                    unsigned short* __restrict__ yb) {
    const int dir = blockIdx.y;
    const float* norm_w = dir ? nw1 : nw0;
    const int row = blockIdx.x;
    const int tid = threadIdx.x;
    const unsigned short* z = megaA + (size_t)row * QKVS + 1536 + dir * DINPROJ;
    const unsigned short* yr = y16 + (size_t)dir * NTOK * DI + (size_t)row * DI;
    float v[4];
    float ss = 0.f;
    #pragma unroll
    for (int i = 0; i < 4; ++i) {
        int c = i * 256 + tid;
        float g = siluf(bf2f(z[c]));
        v[i] = bf2f(yr[c]) * g;
        ss = fmaf(v[i], v[i], ss);
    }
    #pragma unroll
    for (int off = 32; off > 0; off >>= 1) ss += __shfl_xor(ss, off);
    __shared__ float red[4];
    int wid = tid >> 6, lane = tid & 63;
    if (lane == 0) red[wid] = ss;
    __syncthreads();
    ss = red[0] + red[1] + red[2] + red[3];
    float scale = rsqrtf(ss * (1.0f / 1024.0f) + 1e-5f);
    #pragma unroll
    for (int i = 0; i < 4; ++i) {
        int c = i * 256 + tid;
        yb[(size_t)row * 2048 + dir * 1024 + c] = f2bf(v[i] * scale * norm_w[c]);
    }
}

// ------ final: s = h+attn+msum+msum2 (split-K partials) ; LayerNorm(s) ------
__global__ void final_ln_kernel(const float* __restrict__ h, const float* __restrict__ attn,
                                const float* __restrict__ msum, const float* __restrict__ msum2,
                                const float* __restrict__ ln_w, const float* __restrict__ ln_b,
                                float* __restrict__ out) {
    const int row = blockIdx.x;
    const int tid = threadIdx.x;
    size_t base = (size_t)row * DM;
    float v[2];
    float sum = 0.f, sq = 0.f;
    #pragma unroll
    for (int i = 0; i < 2; ++i) {
        int c = i * 256 + tid;
        float s = h[base + c] + attn[base + c] + msum[base + c] + msum2[base + c];
        v[i] = s;
        sum += s;
        sq = fmaf(s, s, sq);
    }
    #pragma unroll
    for (int off = 32; off > 0; off >>= 1) {
        sum += __shfl_xor(sum, off);
        sq += __shfl_xor(sq, off);
    }
    __shared__ float rsum[4], rsq[4];
    int wid = tid >> 6, lane = tid & 63;
    if (lane == 0) { rsum[wid] = sum; rsq[wid] = sq; }
    __syncthreads();
    sum = rsum[0] + rsum[1] + rsum[2] + rsum[3];
    sq = rsq[0] + rsq[1] + rsq[2] + rsq[3];
    float mu = sum * (1.0f / DM);
    float var = sq * (1.0f / DM) - mu * mu;
    float rs = rsqrtf(var + 1e-5f);
    #pragma unroll
    for (int i = 0; i < 2; ++i) {
        int c = i * 256 + tid;
        out[base + c] = (v[i] - mu) * rs * ln_w[c] + ln_b[c];
    }
}

extern "C" void kernel_launch(void* const* d_in, const int* in_sizes, int n_in,
                              void* d_out, int out_size, void* d_ws, size_t ws_size,
                              hipStream_t stream) {
    const float* h          = (const float*)d_in[0];
    const float* attn_in_w  = (const float*)d_in[1];
    const float* attn_in_b  = (const float*)d_in[2];
    const float* attn_out_w = (const float*)d_in[3];
    const float* attn_out_b = (const float*)d_in[4];
    const float* ln_w       = (const float*)d_in[21];
    const float* ln_b       = (const float*)d_in[22];
    float* out = (float*)d_out;

    float* ws = (float*)d_ws;
    unsigned short* megaA = (unsigned short*)ws;
    unsigned short* bufXBC = (unsigned short*)(ws + 12124160);    // 2 dirs bf16
    float* bufDT   = ws + 12124160 + 4718592;
    float* bufY    = bufDT + 131072;        // as bf16: 2 dirs x 4096 x 1024
    float* bufATTN = bufY + 4194304;
    float* gateReg = bufATTN + 2097152;
    float* sReg    = gateReg + 4194304;
    float* bufEdec = sReg + 4194304;        // 2048 floats
    unsigned short* hB = (unsigned short*)(bufEdec + 2048);
    // overlays:
    unsigned short* wBIG   = (unsigned short*)gateReg;            // early
    unsigned short* wAOUT  = wBIG + (size_t)QKVS * DM;
    unsigned short* gatedB = (unsigned short*)gateReg;            // late (after corr)
    unsigned short* actB   = (unsigned short*)sReg;               // early
    float* bufS0           = sReg;                                // scan S dir0
    float* bufS1           = gateReg;                             // scan S dir1 (wBIG dead)
    unsigned short* wC     = (unsigned short*)sReg;               // late
    unsigned short* y16    = (unsigned short*)bufY;               // 2-dir bf16 y
    float* msum            = bufY;                                // outproj split-K partial 0
    float* msum2           = bufY + (size_t)NTOK * DM;            // partial 1 (y16 dead)

    const float* inproj_fwd = (const float*)d_in[5];
    const float* inproj_bwd = (const float*)d_in[13];

    dim3 blk(256);

    // 0) fused cvt
    cvt_all_kernel<<<dim3(S4 / 256), blk, 0, stream>>>(
        h, hB, attn_in_w, wBIG, attn_out_w, wAOUT,
        inproj_fwd, wBIG + (size_t)1536 * DM, inproj_bwd, wBIG + (size_t)3728 * DM);

    // 1) mega projection GEMM (XCD-chunked swizzle; proven structure +
    //    2-way swizzle + occupancy cap 128 regs)
    gemm_mfma_staged<128, true, true, false><<<dim3(8 * 6 * (NTOK / 128)), blk, 0, stream>>>(
        hB, wBIG, attn_in_b, 1536, megaA, NTOK, QKVS, DM);

    // 2) attention
    attn_mfma_kernel<<<dim3(B_ * NHA * (L_ / 64)), blk, 0, stream>>>(megaA, actB);
    // 3) attn_out
    gemm_mfma_staged<64, false, false, false><<<dim3(DM / 64, NTOK / 128), blk, 0, stream>>>(
        actB, wAOUT, attn_out_b, DM, bufATTN, NTOK, DM, DM);

    // 4) dt + conv (both dirs each)
    dt_exact_kernel<<<dim3(NTOK), blk, 0, stream>>>(
        h, inproj_fwd + (size_t)(DINPROJ - NHM) * DM, (const float*)d_in[8],
        inproj_bwd + (size_t)(DINPROJ - NHM) * DM, (const float*)d_in[16], bufDT);
    conv_silu_kernel<<<dim3((NTOK * (CONVCH / 4) + 255) / 256, 2), blk, 0, stream>>>(
        megaA, (const float*)d_in[6], (const float*)d_in[7],
        (const float*)d_in[14], (const float*)d_in[15], bufXBC);

    // 5) scan: both dirs per dispatch
    ssd_chunk_kernel<<<dim3(B_ * NHM * NC, 2), blk, 0, stream>>>(
        bufXBC, bufDT, (const float*)d_in[9], (const float*)d_in[10],
        (const float*)d_in[17], (const float*)d_in[18], y16, bufS0, bufS1, bufEdec);
    ssd_chain_kernel<<<dim3(B_ * NHM, 16, 2), blk, 0, stream>>>(bufS0, bufS1, bufEdec);
    ssd_corr_kernel<<<dim3(B_ * NHM * NC, 2), blk, 0, stream>>>(
        bufXBC, bufDT, (const float*)d_in[9], (const float*)d_in[17], bufS0, bufS1, y16);
    gate_rmsnorm_kernel<<<dim3(NTOK, 2), blk, 0, stream>>>(
        y16, megaA, (const float*)d_in[11], (const float*)d_in[19], gatedB);

    // 6) Combined outproj — split-K=2 (grid.z), partials summed in final_ln
    cvt_outproj_kernel<<<dim3((2 * DM * DI / 8 + 255) / 256), blk, 0, stream>>>(
        (const float*)d_in[12], (const float*)d_in[20], wC);
    gemm_mfma_staged<64, false, false, true><<<dim3(DM / 64, NTOK / 128, 2), blk, 0, stream>>>(
        gatedB, wC, nullptr, 0, msum, NTOK, DM, 2048);

    final_ln_kernel<<<dim3(NTOK), blk, 0, stream>>>(
        h, bufATTN, msum, msum2, ln_w, ln_b, out);
}